// Round 5
// baseline (612.619 us; speedup 1.0000x reference)
//
#include <hip/hip_runtime.h>
#include <cstdint>
#include <cstddef>

#define IN_F 4096
#define OUT_F 4096
#define NROWS 8192
#define BM 256
#define BN 256
#define BK 32
#define NT (IN_F / BK)   // 128 K-tiles

typedef float f32x4 __attribute__((ext_vector_type(4)));
typedef short s16x8 __attribute__((ext_vector_type(8)));

// round-to-nearest-even fp32 -> bf16
__device__ inline unsigned short f2bf_rne(float f) {
    unsigned int u = __float_as_uint(f);
    u += 0x7FFFu + ((u >> 16) & 1u);
    return (unsigned short)(u >> 16);
}

// Fused: blocks [0, 8192) build W; blocks [8192, 24576) convert x to bf16.
// w[o][t] = 2*norm(o)*sin(pi*(o+1)*(2t+1)/8192); integer-exact reduction mod 16384.
__global__ void prep(const float* __restrict__ x, const float* __restrict__ fc,
                     unsigned short* __restrict__ wb, unsigned short* __restrict__ xb) {
    const int b = blockIdx.x;
    if (b < OUT_F * IN_F / 8 / 256) {
        int gid = b * 256 + threadIdx.x;
        int o = gid >> 9;
        int t0 = (gid & 511) << 3;
        int k = (int)fc[o];
        float amp = 2.0f * rsqrtf(2.0f * (float)IN_F * ((k == 0) ? 2.0f : 1.0f));
        unsigned int op1 = (unsigned int)(k + 1);
        union { s16x8 v; unsigned short s[8]; } p;
#pragma unroll
        for (int j = 0; j < 8; ++j) {
            unsigned int t = (unsigned int)(t0 + j);
            unsigned int r = (op1 * (2u * t + 1u)) & 16383u;
            float ang = (float)r * 3.83495196971410293e-4f;  // pi/8192
            p.s[j] = f2bf_rne(amp * __sinf(ang));
        }
        *reinterpret_cast<s16x8*>(&wb[(size_t)gid * 8]) = p.v;
    } else {
        size_t gid = (size_t)(b - OUT_F * IN_F / 8 / 256) * 256 + threadIdx.x;
        const f32x4* xv = reinterpret_cast<const f32x4*>(x) + gid * 2;
        f32x4 a = xv[0], c = xv[1];
        union { s16x8 v; unsigned short s[8]; } p;
        p.s[0] = f2bf_rne(a[0]); p.s[1] = f2bf_rne(a[1]);
        p.s[2] = f2bf_rne(a[2]); p.s[3] = f2bf_rne(a[3]);
        p.s[4] = f2bf_rne(c[0]); p.s[5] = f2bf_rne(c[1]);
        p.s[6] = f2bf_rne(c[2]); p.s[7] = f2bf_rne(c[3]);
        *reinterpret_cast<s16x8*>(&xb[gid * 8]) = p.v;
    }
}

__device__ inline void wg_barrier() {
    asm volatile("" ::: "memory");
    __builtin_amdgcn_s_barrier();
    asm volatile("" ::: "memory");
}

#define GLD(gsrc, ldst) __builtin_amdgcn_global_load_lds( \
    (const __attribute__((address_space(1))) unsigned int*)(gsrc), \
    (__attribute__((address_space(3))) unsigned int*)(ldst), 16, 0, 0)

// Stage B K-tile T into buf[T&3] (16KB). Proven 0-conflict swizzle (R2):
// granule p holds element (row=p>>2, kchunk=(p&3)^((p>>3)&3)).
#define STAGE_B(T) do { \
    const int _sb = ((T) & 3) * 16384; \
    const int _sk = (T) * BK; \
    GLD(gB + _sk, (char*)lds + _sb + ldsB0); \
    GLD(gB2 + _sk, (char*)lds + _sb + ldsB1); \
} while (0)

// Load A fragments for K-tile T directly global -> registers (8 x dwordx4).
#define LOADA(R, T) do { \
    const unsigned short* _p = gAr + (size_t)(T) * BK; \
    R[0] = *(const s16x8*)(_p); \
    R[1] = *(const s16x8*)(_p + 1 * 16 * IN_F); \
    R[2] = *(const s16x8*)(_p + 2 * 16 * IN_F); \
    R[3] = *(const s16x8*)(_p + 3 * 16 * IN_F); \
    R[4] = *(const s16x8*)(_p + 4 * 16 * IN_F); \
    R[5] = *(const s16x8*)(_p + 5 * 16 * IN_F); \
    R[6] = *(const s16x8*)(_p + 6 * 16 * IN_F); \
    R[7] = *(const s16x8*)(_p + 7 * 16 * IN_F); \
} while (0)

#define MFMA1(d, a, b) d = __builtin_amdgcn_mfma_f32_16x16x32_bf16(a, b, d, 0, 0, 0)

// One K-tile: {ds_read B frags; issue A(t+1)->RNXT; stage B(t+3);
// vmcnt(VM) [retires A(t) + B(t+1)]; lgkm(0); 32 MFMA; barrier}.
#define TILE(T, RCUR, RNXT, DO_STAGE, DO_LOADA, VM) do { \
    const int _bb = ((T) & 3) * 16384; \
    s16x8 b0 = *(const s16x8*)((const char*)lds + _bb + boff + 0); \
    s16x8 b1 = *(const s16x8*)((const char*)lds + _bb + boff + 1024); \
    s16x8 b2 = *(const s16x8*)((const char*)lds + _bb + boff + 2048); \
    s16x8 b3 = *(const s16x8*)((const char*)lds + _bb + boff + 3072); \
    if (DO_LOADA) LOADA(RNXT, (T) + 1); \
    if (DO_STAGE) STAGE_B((T) + 3); \
    asm volatile("s_waitcnt vmcnt(" #VM ")" ::: "memory"); \
    asm volatile("s_waitcnt lgkmcnt(0)" ::: "memory"); \
    __builtin_amdgcn_sched_barrier(0); \
    __builtin_amdgcn_s_setprio(1); \
    MFMA1(acc[0][0], RCUR[0], b0); MFMA1(acc[0][1], RCUR[0], b1); \
    MFMA1(acc[0][2], RCUR[0], b2); MFMA1(acc[0][3], RCUR[0], b3); \
    MFMA1(acc[1][0], RCUR[1], b0); MFMA1(acc[1][1], RCUR[1], b1); \
    MFMA1(acc[1][2], RCUR[1], b2); MFMA1(acc[1][3], RCUR[1], b3); \
    MFMA1(acc[2][0], RCUR[2], b0); MFMA1(acc[2][1], RCUR[2], b1); \
    MFMA1(acc[2][2], RCUR[2], b2); MFMA1(acc[2][3], RCUR[2], b3); \
    MFMA1(acc[3][0], RCUR[3], b0); MFMA1(acc[3][1], RCUR[3], b1); \
    MFMA1(acc[3][2], RCUR[3], b2); MFMA1(acc[3][3], RCUR[3], b3); \
    MFMA1(acc[4][0], RCUR[4], b0); MFMA1(acc[4][1], RCUR[4], b1); \
    MFMA1(acc[4][2], RCUR[4], b2); MFMA1(acc[4][3], RCUR[4], b3); \
    MFMA1(acc[5][0], RCUR[5], b0); MFMA1(acc[5][1], RCUR[5], b1); \
    MFMA1(acc[5][2], RCUR[5], b2); MFMA1(acc[5][3], RCUR[5], b3); \
    MFMA1(acc[6][0], RCUR[6], b0); MFMA1(acc[6][1], RCUR[6], b1); \
    MFMA1(acc[6][2], RCUR[6], b2); MFMA1(acc[6][3], RCUR[6], b3); \
    MFMA1(acc[7][0], RCUR[7], b0); MFMA1(acc[7][1], RCUR[7], b1); \
    MFMA1(acc[7][2], RCUR[7], b2); MFMA1(acc[7][3], RCUR[7], b3); \
    __builtin_amdgcn_s_setprio(0); \
    wg_barrier(); \
} while (0)

__global__ __launch_bounds__(512, 2) void gemm_dst(
        const unsigned short* __restrict__ xb, const unsigned short* __restrict__ wb,
        const float* __restrict__ bias, float* __restrict__ out) {
    // B-only LDS: 4-deep circular buffer of 16KB K-tiles = 64 KB
    __shared__ unsigned short lds[32768];

    const int tid = threadIdx.x;
    const int lane = tid & 63;
    const int wave = tid >> 6;
    const int wave_m = wave >> 2;   // 0..1 -> 128-row half
    const int wave_n = wave & 3;    // 0..3 -> 64-col quarter
    const int lr = lane & 15;
    const int kq = lane >> 4;

    const int bid = blockIdx.x;
    // XCD swizzle: 512 wgs, 64 per XCD; 16 consecutive share the A row-panel
    const int swz = (bid & 7) * 64 + (bid >> 3);
    const int brow = (swz >> 4) * BM;   // 32 row panels
    const int bcol = (swz & 15) * BN;   // 16 col panels

    // ---- B stage addressing (R2-proven) ----
    const int srow = tid >> 2;
    const int skq = (tid & 3) ^ ((tid >> 3) & 3);
    const unsigned short* gB  = wb + (size_t)(bcol + srow) * IN_F + skq * 8;
    const unsigned short* gB2 = gB + (size_t)128 * IN_F;
    const int ldsB0 = tid * 16;
    const int ldsB1 = tid * 16 + 8192;

    // ---- B ds_read addressing (R2-proven 0-conflict) ----
    const int colsw = ((kq ^ ((lr >> 1) & 3)) << 4);
    const int boff = (wave_n * 64 + lr) * 64 + colsw;   // frag n at +1024

    // ---- A direct-global fragment base: row = brow + wave_m*128 + m*16 + lr,
    // k = kt + kq*8 (per-lane 16B contiguous) ----
    const unsigned short* gAr = xb + (size_t)(brow + wave_m * 128 + lr) * IN_F + kq * 8;

    f32x4 acc[8][4];
#pragma unroll
    for (int m = 0; m < 8; ++m)
#pragma unroll
        for (int n = 0; n < 4; ++n)
            acc[m][n] = (f32x4){0.f, 0.f, 0.f, 0.f};

    s16x8 A0[8], A1[8];

    // ---- prologue: stage B tiles 0..2, load A(0); full drain once ----
    STAGE_B(0); STAGE_B(1); STAGE_B(2);
    LOADA(A0, 0);
    asm volatile("s_waitcnt vmcnt(0)" ::: "memory");
    wg_barrier();

    // ---- main loop (2-tile unroll for A cur/next register swap) ----
    for (int t = 0; t < 124; t += 2) {
        TILE(t,     A0, A1, 1, 1, 12);
        TILE(t + 1, A1, A0, 1, 1, 12);
    }
    TILE(124, A0, A1, 1, 1, 12);   // stages B(127)
    TILE(125, A1, A0, 0, 1, 10);
    TILE(126, A0, A1, 0, 1, 8);
    TILE(127, A1, A0, 0, 0, 0);

    // ---- epilogue: C = acc + bias; 16x16 D layout: col=lane&15, row=(lane>>4)*4+j ----
    const int ccol0 = bcol + wave_n * 64 + lr;
    const int crow0 = brow + wave_m * 128 + kq * 4;
    float bv[4];
#pragma unroll
    for (int n = 0; n < 4; ++n) bv[n] = bias[ccol0 + n * 16];
#pragma unroll
    for (int m = 0; m < 8; ++m) {
#pragma unroll
        for (int j = 0; j < 4; ++j) {
            float* orow = out + (size_t)(crow0 + m * 16 + j) * OUT_F + ccol0;
#pragma unroll
            for (int n = 0; n < 4; ++n)
                orow[n * 16] = acc[m][n][j] + bv[n];
        }
    }
}

// last-resort fallback if workspace is too small (naive on-the-fly DST)
__global__ void fallback_kernel(const float* __restrict__ x, const float* __restrict__ fc,
                                const float* __restrict__ bias, float* __restrict__ out) {
    __shared__ float xrow[IN_F];
    const int o = blockIdx.x * 256 + threadIdx.x;
    const int n = blockIdx.y;
    for (int i = threadIdx.x; i < IN_F; i += 256)
        xrow[i] = x[(size_t)n * IN_F + i];
    __syncthreads();
    const int k = (int)fc[o];
    const float amp = 2.0f * rsqrtf(2.0f * (float)IN_F * ((k == 0) ? 2.0f : 1.0f));
    const unsigned int op1 = (unsigned int)(k + 1);
    float s = 0.f;
    for (int t = 0; t < IN_F; ++t) {
        unsigned int r = (op1 * (2u * (unsigned int)t + 1u)) & 16383u;
        s += xrow[t] * __sinf((float)r * 3.83495196971410293e-4f);
    }
    out[(size_t)n * OUT_F + o] = amp * s + bias[o];
}

extern "C" void kernel_launch(void* const* d_in, const int* in_sizes, int n_in,
                              void* d_out, int out_size, void* d_ws, size_t ws_size,
                              hipStream_t stream) {
    const float* x    = (const float*)d_in[0];
    const float* fc   = (const float*)d_in[1];
    const float* bias = (const float*)d_in[2];
    float* out = (float*)d_out;

    const size_t WBYTES = (size_t)OUT_F * IN_F * 2;   // 32 MB
    const size_t XBYTES = (size_t)NROWS * IN_F * 2;   // 64 MB

    if (ws_size >= WBYTES + XBYTES) {
        unsigned short* wb = (unsigned short*)d_ws;
        unsigned short* xb = (unsigned short*)((char*)d_ws + WBYTES);
        const int wgrid = OUT_F * IN_F / 8 / 256;           // 8192
        const int xgrid = NROWS * IN_F / 8 / 256;           // 16384
        prep<<<wgrid + xgrid, 256, 0, stream>>>(x, fc, wb, xb);
        const int grid = (NROWS / BM) * (OUT_F / BN);       // 512
        gemm_dst<<<grid, 512, 0, stream>>>(xb, wb, bias, out);
    } else {
        dim3 g(OUT_F / 256, NROWS);
        fallback_kernel<<<g, 256, 0, stream>>>(x, fc, bias, out);
    }
}

// Round 6
// 279.421 us; speedup vs baseline: 2.1925x; 2.1925x over previous
//
#include <hip/hip_runtime.h>
#include <cstdint>
#include <cstddef>

#define IN_F 4096
#define OUT_F 4096
#define NROWS 8192
#define BM 256
#define BN 256
#define BK 32
#define NT (IN_F / BK)   // 128 K-tiles

typedef float f32x4 __attribute__((ext_vector_type(4)));
typedef short s16x8 __attribute__((ext_vector_type(8)));

// round-to-nearest-even fp32 -> bf16
__device__ inline unsigned short f2bf_rne(float f) {
    unsigned int u = __float_as_uint(f);
    u += 0x7FFFu + ((u >> 16) & 1u);
    return (unsigned short)(u >> 16);
}

// Fused: blocks [0, 8192) build W; blocks [8192, 24576) convert x to bf16.
// w[o][t] = 2*norm(o)*sin(pi*(o+1)*(2t+1)/8192); integer-exact reduction mod 16384.
__global__ void prep(const float* __restrict__ x, const float* __restrict__ fc,
                     unsigned short* __restrict__ wb, unsigned short* __restrict__ xb) {
    const int b = blockIdx.x;
    if (b < OUT_F * IN_F / 8 / 256) {
        int gid = b * 256 + threadIdx.x;
        int o = gid >> 9;
        int t0 = (gid & 511) << 3;
        int k = (int)fc[o];
        float amp = 2.0f * rsqrtf(2.0f * (float)IN_F * ((k == 0) ? 2.0f : 1.0f));
        unsigned int op1 = (unsigned int)(k + 1);
        union { s16x8 v; unsigned short s[8]; } p;
#pragma unroll
        for (int j = 0; j < 8; ++j) {
            unsigned int t = (unsigned int)(t0 + j);
            unsigned int r = (op1 * (2u * t + 1u)) & 16383u;
            float ang = (float)r * 3.83495196971410293e-4f;  // pi/8192
            p.s[j] = f2bf_rne(amp * __sinf(ang));
        }
        *reinterpret_cast<s16x8*>(&wb[(size_t)gid * 8]) = p.v;
    } else {
        size_t gid = (size_t)(b - OUT_F * IN_F / 8 / 256) * 256 + threadIdx.x;
        const f32x4* xv = reinterpret_cast<const f32x4*>(x) + gid * 2;
        f32x4 a = xv[0], c = xv[1];
        union { s16x8 v; unsigned short s[8]; } p;
        p.s[0] = f2bf_rne(a[0]); p.s[1] = f2bf_rne(a[1]);
        p.s[2] = f2bf_rne(a[2]); p.s[3] = f2bf_rne(a[3]);
        p.s[4] = f2bf_rne(c[0]); p.s[5] = f2bf_rne(c[1]);
        p.s[6] = f2bf_rne(c[2]); p.s[7] = f2bf_rne(c[3]);
        *reinterpret_cast<s16x8*>(&xb[gid * 8]) = p.v;
    }
}

__device__ inline void wg_barrier() {
    asm volatile("" ::: "memory");
    __builtin_amdgcn_s_barrier();
    asm volatile("" ::: "memory");
}

#define GLD(gsrc, ldst) __builtin_amdgcn_global_load_lds( \
    (const __attribute__((address_space(1))) unsigned int*)(gsrc), \
    (__attribute__((address_space(3))) unsigned int*)(ldst), 16, 0, 0)

// Stage A/B K-tile T into buf[T&3]. 256 threads x 4 GLD = 16KB each.
// Proven 0-conflict layout: granule g holds (row=g>>2, kchunk=(g&3)^((g>>3)&3)).
#define STAGE_A(T) do { \
    char* _d = (char*)lds + (((T) & 3) << 15) + tid * 16; \
    const unsigned short* _s = gA + (size_t)(T) * BK; \
    GLD(_s,                       _d); \
    GLD(_s + (size_t)64 * IN_F,  _d + 4096); \
    GLD(_s + (size_t)128 * IN_F, _d + 8192); \
    GLD(_s + (size_t)192 * IN_F, _d + 12288); \
} while (0)

#define STAGE_B(T) do { \
    char* _d = (char*)lds + (((T) & 3) << 15) + 16384 + tid * 16; \
    const unsigned short* _s = gB + (size_t)(T) * BK; \
    GLD(_s,                       _d); \
    GLD(_s + (size_t)64 * IN_F,  _d + 4096); \
    GLD(_s + (size_t)128 * IN_F, _d + 8192); \
    GLD(_s + (size_t)192 * IN_F, _d + 12288); \
} while (0)

#define MFMA1(d, a, b) d = __builtin_amdgcn_mfma_f32_16x16x32_bf16(a, b, d, 0, 0, 0)

// One K-tile: {16 ds_read_b128; stage(t+3) 8 GLD; 64 MFMA; vmcnt(VM); barrier}.
// Compiler free to interleave (counted lgkm auto-inserted); no setprio/sched pins.
#define TILE(T, DO_STAGE, VM) do { \
    const char* _bb = (const char*)lds + (((T) & 3) << 15); \
    s16x8 af[8], bf[8]; \
    _Pragma("unroll") \
    for (int m = 0; m < 8; ++m) af[m] = *(const s16x8*)(_bb + aoff + m * 1024); \
    _Pragma("unroll") \
    for (int n = 0; n < 8; ++n) bf[n] = *(const s16x8*)(_bb + boff + n * 1024); \
    if (DO_STAGE) { STAGE_A((T) + 3); STAGE_B((T) + 3); } \
    _Pragma("unroll") \
    for (int m = 0; m < 8; ++m) { \
        _Pragma("unroll") \
        for (int n = 0; n < 8; ++n) MFMA1(acc[m][n], af[m], bf[n]); \
    } \
    asm volatile("s_waitcnt vmcnt(" #VM ")" ::: "memory"); \
    wg_barrier(); \
} while (0)

__global__ __launch_bounds__(256, 1) void gemm_dst(
        const unsigned short* __restrict__ xb, const unsigned short* __restrict__ wb,
        const float* __restrict__ bias, float* __restrict__ out) {
    // 4-deep circular buffer: [buf][A 16KB | B 16KB] = 128 KB
    __shared__ unsigned short lds[65536];

    const int tid = threadIdx.x;
    const int lane = tid & 63;
    const int wave = tid >> 6;
    const int wave_m = wave >> 1;   // 0..1 -> 128-row half
    const int wave_n = wave & 1;    // 0..1 -> 128-col half
    const int lr = lane & 15;
    const int kq = lane >> 4;

    const int bid = blockIdx.x;
    // XCD swizzle: 512 wgs, 64 per XCD; 16 consecutive share the A row-panel
    const int swz = (bid & 7) * 64 + (bid >> 3);
    const int brow = (swz >> 4) * BM;   // 32 row panels
    const int bcol = (swz & 15) * BN;   // 16 col panels

    // ---- stage addressing (0-conflict proven): thread tid, GLD j ->
    // row = j*64 + (tid>>2), kchunk = (tid&3)^((tid>>3)&3) ----
    const int srow = tid >> 2;
    const int skq = (tid & 3) ^ ((tid >> 3) & 3);
    const unsigned short* gA = xb + (size_t)(brow + srow) * IN_F + skq * 8;
    const unsigned short* gB = wb + (size_t)(bcol + srow) * IN_F + skq * 8;

    // ---- ds_read addressing (0-conflict proven): row R -> byte
    // R*64 + ((kq ^ ((R>>1)&3))<<4); R = wave_**128 + frag*16 + lr, and
    // (frag*16)>>1 & 3 == 0, so the XOR term is per-lane constant ----
    const int colsw = ((kq ^ ((lr >> 1) & 3)) << 4);
    const int aoff = (wave_m * 128 + lr) * 64 + colsw;           // + m*1024
    const int boff = 16384 + (wave_n * 128 + lr) * 64 + colsw;   // + n*1024

    f32x4 acc[8][8];
#pragma unroll
    for (int m = 0; m < 8; ++m)
#pragma unroll
        for (int n = 0; n < 8; ++n)
            acc[m][n] = (f32x4){0.f, 0.f, 0.f, 0.f};

    // ---- prologue: stage tiles 0,1,2 (24 GLD); vmcnt(16) retires tile 0 ----
    STAGE_A(0); STAGE_B(0);
    STAGE_A(1); STAGE_B(1);
    STAGE_A(2); STAGE_B(2);
    asm volatile("s_waitcnt vmcnt(16)" ::: "memory");
    wg_barrier();

    // ---- main loop: compute buf[t&3], stage tile t+3 ----
#pragma unroll 2
    for (int t = 0; t < NT - 3; ++t) {
        TILE(t, 1, 16);
    }
    // ---- tail: drain 8 -> 0 ----
    TILE(NT - 3, 0, 8);
    TILE(NT - 2, 0, 0);
    TILE(NT - 1, 0, 0);

    // ---- epilogue: C = acc + bias; 16x16 D layout: col=lane&15, row=(lane>>4)*4+j ----
    const int ccol0 = bcol + wave_n * 128 + lr;
    const int crow0 = brow + wave_m * 128 + kq * 4;
    float bv[8];
#pragma unroll
    for (int n = 0; n < 8; ++n) bv[n] = bias[ccol0 + n * 16];
#pragma unroll
    for (int m = 0; m < 8; ++m) {
#pragma unroll
        for (int j = 0; j < 4; ++j) {
            float* orow = out + (size_t)(crow0 + m * 16 + j) * OUT_F + ccol0;
#pragma unroll
            for (int n = 0; n < 8; ++n)
                orow[n * 16] = acc[m][n][j] + bv[n];
        }
    }
}

// last-resort fallback if workspace is too small (naive on-the-fly DST)
__global__ void fallback_kernel(const float* __restrict__ x, const float* __restrict__ fc,
                                const float* __restrict__ bias, float* __restrict__ out) {
    __shared__ float xrow[IN_F];
    const int o = blockIdx.x * 256 + threadIdx.x;
    const int n = blockIdx.y;
    for (int i = threadIdx.x; i < IN_F; i += 256)
        xrow[i] = x[(size_t)n * IN_F + i];
    __syncthreads();
    const int k = (int)fc[o];
    const float amp = 2.0f * rsqrtf(2.0f * (float)IN_F * ((k == 0) ? 2.0f : 1.0f));
    const unsigned int op1 = (unsigned int)(k + 1);
    float s = 0.f;
    for (int t = 0; t < IN_F; ++t) {
        unsigned int r = (op1 * (2u * (unsigned int)t + 1u)) & 16383u;
        s += xrow[t] * __sinf((float)r * 3.83495196971410293e-4f);
    }
    out[(size_t)n * OUT_F + o] = amp * s + bias[o];
}

extern "C" void kernel_launch(void* const* d_in, const int* in_sizes, int n_in,
                              void* d_out, int out_size, void* d_ws, size_t ws_size,
                              hipStream_t stream) {
    const float* x    = (const float*)d_in[0];
    const float* fc   = (const float*)d_in[1];
    const float* bias = (const float*)d_in[2];
    float* out = (float*)d_out;

    const size_t WBYTES = (size_t)OUT_F * IN_F * 2;   // 32 MB
    const size_t XBYTES = (size_t)NROWS * IN_F * 2;   // 64 MB

    if (ws_size >= WBYTES + XBYTES) {
        unsigned short* wb = (unsigned short*)d_ws;
        unsigned short* xb = (unsigned short*)((char*)d_ws + WBYTES);
        const int wgrid = OUT_F * IN_F / 8 / 256;           // 8192
        const int xgrid = NROWS * IN_F / 8 / 256;           // 16384
        prep<<<wgrid + xgrid, 256, 0, stream>>>(x, fc, wb, xb);
        const int grid = (NROWS / BM) * (OUT_F / BN);       // 512
        gemm_dst<<<grid, 256, 0, stream>>>(xb, wb, bias, out);
    } else {
        dim3 g(OUT_F / 256, NROWS);
        fallback_kernel<<<g, 256, 0, stream>>>(x, fc, bias, out);
    }
}